// Round 4
// baseline (139.546 us; speedup 1.0000x reference)
//
#include <hip/hip_runtime.h>
#include <math.h>

#define B 16
#define N 200
#define HID 64
#define NH 2
#define D 32
#define EPSF 1e-12f
#define LOG_EPSF 1e-24f

// 1/sqrt(32)
#define RSQRT_D 0.17677669529663687f

__device__ __forceinline__ float dpp_qperm_add(float x, const int ctrl) {
    // x + quad_perm(x): pure-VALU cross-lane within quads, no LDS, no waits
    int yi;
    switch (ctrl) {
        case 0xB1: yi = __builtin_amdgcn_mov_dpp(__float_as_int(x), 0xB1, 0xF, 0xF, true); break;
        default:   yi = __builtin_amdgcn_mov_dpp(__float_as_int(x), 0x4E, 0xF, 0xF, true); break;
    }
    return x + __int_as_float(yi);
}

// ---------------- Kernel 1: projections + folded pos + order/dist scalars ----
__global__ __launch_bounds__(256) void k_proj(
    const float* __restrict__ x,
    const float* __restrict__ pk,
    const float* __restrict__ pv,
    const float* __restrict__ Wq, const float* __restrict__ bq,
    const float* __restrict__ Wk, const float* __restrict__ bk,
    const float* __restrict__ Wv, const float* __restrict__ bv,
    const float* __restrict__ order_w, const float* __restrict__ dist_w,
    float* __restrict__ q,
    float* __restrict__ kp,
    float* __restrict__ vp,
    float* __restrict__ qo, float* __restrict__ ko,
    float* __restrict__ qd, float* __restrict__ kd)
{
    __shared__ float sX[4][HID];
    const int tid = threadIdx.x;
    const int sub = tid >> 6;
    const int o   = tid & 63;
    const int row = blockIdx.x * 4 + sub;

    sX[sub][o] = x[row * HID + o];
    __syncthreads();

    float qv = bq[o], kv = bk[o], vv = bv[o];
    #pragma unroll 8
    for (int c = 0; c < HID; ++c) {
        const float xv = sX[sub][c];
        qv = fmaf(xv, Wq[o * HID + c], qv);
        kv = fmaf(xv, Wk[o * HID + c], kv);
        vv = fmaf(xv, Wv[o * HID + c], vv);
    }
    q [row * HID + o] = qv;
    kp[row * HID + o] = kv + pk[row * HID + o];
    vp[row * HID + o] = vv + pv[row * HID + o];

    const int d = o & 31;
    float qov = qv * order_w[d];
    float kov = kv * order_w[D + d];
    float qdv = qv * dist_w[d];
    float kdv = kv * dist_w[D + d];
    #pragma unroll
    for (int m = 16; m >= 1; m >>= 1) {
        qov += __shfl_xor(qov, m);
        kov += __shfl_xor(kov, m);
        qdv += __shfl_xor(qdv, m);
        kdv += __shfl_xor(kdv, m);
    }
    if (d == 0) {
        const int bb = row / N;
        const int ii = row - bb * N;
        const int h  = o >> 5;
        const int idx = (bb * NH + h) * N + ii;
        qo[idx] = qov;  ko[idx] = kov;
        qd[idx] = qdv;  kd[idx] = kdv;
    }
}

// ---------------- Kernel 2: fused scores + softmax + context --------------
// grid = B*N blocks (one per (b,i)); 128 threads = 2 waves; wave w owns the
// j-range [w*100, w*100+100). Both heads handled in one block so every global
// load instruction covers 64 lanes x 16B = 1 KB CONTIGUOUS (4 full rows).
// Lane layout: lane = jj*16 + c (jj = row-in-quad-of-rows 0..3, c = float4
// column 0..15; head = c>>3). Streaming loops contain NO cross-lane/LDS-wait
// dependencies: dot partials are pair-reduced with DPP quad-perm adds (VALU)
// and spilled with a single fire-and-forget ds_write per iteration.
__global__ __launch_bounds__(128, 6) void k_attn(
    const float* __restrict__ q, const float* __restrict__ kp,
    const float* __restrict__ vp,
    const float* __restrict__ tk,     // [B,N,N,HID]
    const float* __restrict__ tv,
    const float* __restrict__ amask,  // [B,1,N,N]
    const float* __restrict__ qo, const float* __restrict__ ko,
    const float* __restrict__ qd, const float* __restrict__ kd,
    const float* __restrict__ order_b, const float* __restrict__ dist_b,
    const float* __restrict__ scalar,
    float* __restrict__ ctx)          // [B*N, HID]
{
    // W2: dot partials, skewed strides for conflict-free access.
    // addr = p*520 + head*272 + j  (banks: 8p + 16h + j mod 32)
    __shared__ float  W2[1024];
    __shared__ float  SA[512];        // aux additive term [head][j] (stride 256)
    __shared__ float  SP[512];        // probs [head][j] (stride 256)
    __shared__ float4 CP[128];        // per-thread ctx partials

    const int tid  = threadIdx.x;
    const int w    = tid >> 6;        // wave id = j-half
    const int lane = tid & 63;
    const int jj   = lane >> 4;       // 0..3
    const int c    = lane & 15;       // float4 column in full row
    const int head = c >> 3;
    const int p    = (c >> 2) & 1;

    const int bi = blockIdx.x;        // b*N + i
    const int b  = bi / N;
    const int i  = bi - b * N;

    // wave-uniform scalars
    const float* qoB = qo + (size_t)(2 * b) * N;
    const float* koB = ko + (size_t)(2 * b) * N;
    const float* qdB = qd + (size_t)(2 * b) * N;
    const float* kdB = kd + (size_t)(2 * b) * N;
    const float ob  = order_b[0];
    const float db  = dist_b[0];
    const float sc  = scalar[0];
    const float sc2h = 0.5f * sc * sc;
    const float qoi0 = qoB[i],       qoi1 = qoB[N + i];
    const float qdi0 = qdB[i],       qdi1 = qdB[N + i];
    const float* mb  = amask + (size_t)bi * N;

    // per-lane q fragment, pre-scaled by 1/sqrt(D)
    float4 qf = ((const float4*)(q + (size_t)bi * HID))[c];
    qf.x *= RSQRT_D; qf.y *= RSQRT_D; qf.z *= RSQRT_D; qf.w *= RSQRT_D;

    // row-base pointers for this wave's j-half (contiguous 1KB per iter)
    const float4* kpR = (const float4*)(kp + ((size_t)b * N + w * 100) * HID);
    const float4* tkR = (const float4*)(tk + (((size_t)b * N + i) * N + w * 100) * HID);
    const float4* vpR = (const float4*)(vp + ((size_t)b * N + w * 100) * HID);
    const float4* tvR = (const float4*)(tv + (((size_t)b * N + i) * N + w * 100) * HID);

    // ---- phase A: aux additive term per (h,j): transcendentals + gathers ----
    #pragma unroll
    for (int r = 0; r < 4; ++r) {
        const int e = tid + 128 * r;          // e = h*200 + j
        if (e < 2 * N) {
            const int h = (e >= N);
            const int j = e - (h ? N : 0);
            const float lo = (h ? qoi1 : qoi0) + koB[e] + ob;
            const float xs = (j > i) ? -lo : lo;
            const float eo = -log1pf(expf(xs));
            const float pd = (h ? qdi1 : qdi0) + kdB[e] + db;
            const float gd = logf((float)(j > i ? j - i : i - j) + 1.0f);
            const float dv = gd - pd;
            SA[h * 256 + j] = (eo - sc2h * dv * dv) * RSQRT_D + mb[j];
        }
    }

    // ---- phase B: streaming dot partials (no cross-lane waits in loop) ----
    const int wbase = p * 520 + head * 272 + w * 100 + jj;
    #pragma unroll
    for (int it = 0; it < 25; ++it) {
        const float4 kv  = kpR[it * 64 + lane];
        const float4 tkv = tkR[it * 64 + lane];
        float part = qf.x * (kv.x + tkv.x) + qf.y * (kv.y + tkv.y)
                   + qf.z * (kv.z + tkv.z) + qf.w * (kv.w + tkv.w);
        part = dpp_qperm_add(part, 0xB1);     // xor 1 within quad
        part = dpp_qperm_add(part, 0x4E);     // xor 2 within quad
        if ((lane & 3) == 0)                  // 16 active lanes, 16 distinct banks
            W2[wbase + it * 4] = part;
    }
    __syncthreads();

    // ---- softmax: wave w handles head w over all 200 j ----
    {
        const int hb272 = w * 272;
        const int hb256 = w * 256;
        const float s0 = W2[hb272 + lane]       + W2[520 + hb272 + lane]       + SA[hb256 + lane];
        const float s1 = W2[hb272 + lane + 64]  + W2[520 + hb272 + lane + 64]  + SA[hb256 + lane + 64];
        const float s2 = W2[hb272 + lane + 128] + W2[520 + hb272 + lane + 128] + SA[hb256 + lane + 128];
        const float s3 = (lane < 8) ? (W2[hb272 + lane + 192] + W2[520 + hb272 + lane + 192]
                                       + SA[hb256 + lane + 192]) : -INFINITY;
        float m = fmaxf(fmaxf(s0, s1), fmaxf(s2, s3));
        #pragma unroll
        for (int k = 32; k >= 1; k >>= 1) m = fmaxf(m, __shfl_xor(m, k));
        const float e0 = expf(s0 - m);
        const float e1 = expf(s1 - m);
        const float e2 = expf(s2 - m);
        const float e3 = (lane < 8) ? expf(s3 - m) : 0.0f;
        float t = e0 + e1 + e2 + e3;
        #pragma unroll
        for (int k = 32; k >= 1; k >>= 1) t += __shfl_xor(t, k);
        const float rinv = 1.0f / t;
        SP[hb256 + lane]       = e0 * rinv;
        SP[hb256 + lane + 64]  = e1 * rinv;
        SP[hb256 + lane + 128] = e2 * rinv;
        if (lane < 8) SP[hb256 + lane + 192] = e3 * rinv;
    }
    __syncthreads();

    // ---- phase C: ctx partials (again pure streaming) ----
    float4 acc = make_float4(0.f, 0.f, 0.f, 0.f);
    const int pbase = head * 256 + w * 100 + jj;
    #pragma unroll
    for (int it = 0; it < 25; ++it) {
        const float pj = SP[pbase + it * 4];
        const float4 vv = vpR[it * 64 + lane];
        const float4 tt = tvR[it * 64 + lane];
        acc.x = fmaf(pj, vv.x + tt.x, acc.x);
        acc.y = fmaf(pj, vv.y + tt.y, acc.y);
        acc.z = fmaf(pj, vv.z + tt.z, acc.z);
        acc.w = fmaf(pj, vv.w + tt.w, acc.w);
    }
    CP[tid] = acc;
    __syncthreads();

    // ---- combine 8 partials per output column, store 256B row ----
    if (tid < 16) {
        float4 s = CP[tid];
        #pragma unroll
        for (int g = 1; g < 8; ++g) {
            const float4 t4 = CP[g * 16 + tid];
            s.x += t4.x; s.y += t4.y; s.z += t4.z; s.w += t4.w;
        }
        ((float4*)(ctx + (size_t)bi * HID))[tid] = s;
    }
}

// ---------------- Kernel 3: output proj + residual + LayerNorm ------------
__global__ __launch_bounds__(256) void k_out(
    const float* __restrict__ ctx, const float* __restrict__ x,
    const float* __restrict__ Wd, const float* __restrict__ bd,
    const float* __restrict__ ln_g, const float* __restrict__ ln_b,
    float* __restrict__ out)
{
    __shared__ float sC[4][HID];
    const int tid = threadIdx.x;
    const int sub = tid >> 6;
    const int o   = tid & 63;
    const int row = blockIdx.x * 4 + sub;

    sC[sub][o] = ctx[row * HID + o];
    __syncthreads();

    float hv = bd[o] + x[row * HID + o];
    #pragma unroll 8
    for (int c = 0; c < HID; ++c)
        hv = fmaf(sC[sub][c], Wd[o * HID + c], hv);

    float sum = hv;
    #pragma unroll
    for (int m = 32; m >= 1; m >>= 1) sum += __shfl_xor(sum, m);
    const float mu = sum * (1.0f / 64.0f);
    const float dv = hv - mu;
    float vs = dv * dv;
    #pragma unroll
    for (int m = 32; m >= 1; m >>= 1) vs += __shfl_xor(vs, m);
    const float var = vs * (1.0f / 64.0f);

    out[row * HID + o] = dv * rsqrtf(var + EPSF) * ln_g[o] + ln_b[o];
}

extern "C" void kernel_launch(void* const* d_in, const int* in_sizes, int n_in,
                              void* d_out, int out_size, void* d_ws, size_t ws_size,
                              hipStream_t stream) {
    const float* x     = (const float*)d_in[0];
    const float* amask = (const float*)d_in[1];
    const float* apk   = (const float*)d_in[2];
    const float* apv   = (const float*)d_in[3];
    const float* tk    = (const float*)d_in[4];
    const float* tv    = (const float*)d_in[5];
    const float* Wq    = (const float*)d_in[6];
    const float* bq    = (const float*)d_in[7];
    const float* Wk    = (const float*)d_in[8];
    const float* bk    = (const float*)d_in[9];
    const float* Wv    = (const float*)d_in[10];
    const float* bv    = (const float*)d_in[11];
    const float* Wd    = (const float*)d_in[12];
    const float* bd    = (const float*)d_in[13];
    const float* order_w = (const float*)d_in[14];
    const float* order_b = (const float*)d_in[15];
    const float* dist_w  = (const float*)d_in[16];
    const float* dist_b  = (const float*)d_in[17];
    const float* scalar  = (const float*)d_in[18];
    const float* ln_g    = (const float*)d_in[19];
    const float* ln_b    = (const float*)d_in[20];

    float* ws = (float*)d_ws;
    const size_t nrow = (size_t)B * N * HID;       // 819200
    float* qbuf  = ws;
    float* kpbuf = ws + nrow;
    float* vpbuf = ws + 2 * nrow;
    float* ctxb  = ws + 3 * nrow;
    float* qob   = ws + 4 * nrow;
    float* kob   = qob + (size_t)B * NH * N;
    float* qdb   = kob + (size_t)B * NH * N;
    float* kdb   = qdb + (size_t)B * NH * N;

    k_proj<<<(B * N) / 4, 256, 0, stream>>>(x, apk, apv, Wq, bq, Wk, bk, Wv, bv,
                                            order_w, dist_w,
                                            qbuf, kpbuf, vpbuf, qob, kob, qdb, kdb);

    k_attn<<<B * N, 128, 0, stream>>>(qbuf, kpbuf, vpbuf, tk, tv, amask,
                                      qob, kob, qdb, kdb,
                                      order_b, dist_b, scalar, ctxb);

    k_out<<<(B * N) / 4, 256, 0, stream>>>(ctxb, x, Wd, bd, ln_g, ln_b,
                                           (float*)d_out);
}